// Round 7
// baseline (158.295 us; speedup 1.0000x reference)
//
#include <hip/hip_runtime.h>

// Problem constants (from reference setup_inputs)
#define BB 4096   // batch
#define SS 256    // sequence length
#define FF 64     // features
#define GG 9      // 3*U gate width
#define DD 8      // LDS staging ring depth (steps); 8 tiles x 4KB = 32KB

#define NEG_LOG2E -1.4426950408889634f
#define TWO_LOG2E  2.8853900817779268f

typedef float f2 __attribute__((ext_vector_type(2)));

#if __has_builtin(__builtin_amdgcn_exp2f)
__device__ __forceinline__ float fast_exp2(float x) { return __builtin_amdgcn_exp2f(x); }
#else
__device__ __forceinline__ float fast_exp2(float x) { return exp2f(x); }
#endif
#if __has_builtin(__builtin_amdgcn_rcpf)
__device__ __forceinline__ float fast_rcp(float x) { return __builtin_amdgcn_rcpf(x); }
#else
__device__ __forceinline__ float fast_rcp(float x) { return 1.0f / x; }
#endif

// Quad-lane DPP helper (verified absmax-0 in R3-R6).
template <int CTRL>
__device__ __forceinline__ float dpp_quad(float v) {
  return __int_as_float(
      __builtin_amdgcn_mov_dpp(__float_as_int(v), CTRL, 0xF, 0xF, true));
}

// Counted vmem wait the compiler cannot collapse (T4). Literal N in string.
#define VMWAIT(n) asm volatile("s_waitcnt vmcnt(" #n ")" ::: "memory")

typedef const unsigned int __attribute__((address_space(1))) * gp_t;
typedef unsigned int __attribute__((address_space(3))) * lp_t;

// -----------------------------------------------------------------------------
// Fully fused GRU. 256 blocks x 1 wave (one per CU), 16 chains/block,
// 4 lanes/chain, 4-way feature split (R5 structure, absmax-0 verified math).
// R7: x is streamed via global_load_lds into an 8-step LDS ring; in-flight
// bytes cost ZERO VGPRs (R6's register ring was collapsed by the allocator
// at VGPR=172 -> latency exposed, VALUBusy 14%). Explicit counted
// s_waitcnt vmcnt(28) keeps 7 tiles (28 ops) in flight across the whole main
// loop -- never draining. Single wave per block -> no barriers anywhere.
// ds_read one step ahead into named A/B register buffers (static indexing).
// -----------------------------------------------------------------------------
__global__ __launch_bounds__(64, 1) void fused_gru_kernel(
    const float* __restrict__ x,           // [B,S,F]
    const float* __restrict__ kernel_w,    // [F,9]
    const float* __restrict__ rec_kernel,  // [3,9]
    const float* __restrict__ bias,        // [2,9]
    const float* __restrict__ dense_w,     // [3,10]
    const float* __restrict__ dense_b,     // [10]
    float* __restrict__ out)               // [B,10]
{
  __shared__ float lds[DD * 1024];     // 8 tiles x 1024 floats (4KB each)

  const int lane = threadIdx.x;        // 0..63
  const int u    = lane & 3;           // quad slot (feature sub-slice / unit)
  const int uc   = (u < 3) ? u : 2;    // lane 3: clamp unit role (benign)
  const int c    = blockIdx.x * 16 + (lane >> 2);  // chain (batch) id

  // ---- input-projection weights for this lane's 16 features (pre-scaled)
  f2 w01[16], w23[16], w45[16], w67[16];
  float w8[16];
#pragma unroll
  for (int j = 0; j < 4; ++j)
#pragma unroll
    for (int e = 0; e < 4; ++e) {
      const int fi = j * 16 + u * 4 + e;   // feature index
      const int sl = j * 4 + e;            // register slot
      const float* kw = kernel_w + fi * GG;
      w01[sl] = (f2){kw[0] * NEG_LOG2E, kw[1] * NEG_LOG2E};
      w23[sl] = (f2){kw[2] * NEG_LOG2E, kw[3] * NEG_LOG2E};
      w45[sl] = (f2){kw[4] * NEG_LOG2E, kw[5] * NEG_LOG2E};
      w67[sl] = (f2){kw[6] * TWO_LOG2E, kw[7] * TWO_LOG2E};
      w8[sl]  = kw[8] * TWO_LOG2E;
    }

  // input bias, pre-scaled AND quartered (quad reduce restores exactly 1x).
  const f2 b01q = {bias[0] * NEG_LOG2E * 0.25f, bias[1] * NEG_LOG2E * 0.25f};
  const f2 b23q = {bias[2] * NEG_LOG2E * 0.25f, bias[3] * NEG_LOG2E * 0.25f};
  const f2 b45q = {bias[4] * NEG_LOG2E * 0.25f, bias[5] * NEG_LOG2E * 0.25f};
  const f2 b67q = {bias[6] * TWO_LOG2E * 0.25f, bias[7] * TWO_LOG2E * 0.25f};
  const float b8q = bias[8] * TWO_LOG2E * 0.25f;

  // recurrent weights/bias for this lane's unit (pre-scaled)
  float wz[3], wr[3], wh[3];
#pragma unroll
  for (int hh = 0; hh < 3; ++hh) {
    wz[hh] = rec_kernel[hh * GG + uc]     * NEG_LOG2E;
    wr[hh] = rec_kernel[hh * GG + 3 + uc] * NEG_LOG2E;
    wh[hh] = rec_kernel[hh * GG + 6 + uc] * TWO_LOG2E;
  }
  const float rbz = bias[GG + uc]     * NEG_LOG2E;
  const float rbr = bias[GG + 3 + uc] * NEG_LOG2E;
  const float rbh = bias[GG + 6 + uc] * TWO_LOG2E;

  float h0 = 0.0f, h1 = 0.0f, h2 = 0.0f, hprev = 0.0f;

  // per-lane global source: chain c, features u*4 + j*16, step s
  const float* gsrc = x + (size_t)c * SS * FF + u * 4;

  // stage tile s: 4x global_load_lds (1KB each; LDS dst = uniform base +
  // lane*16; per-lane global src). Slot = s mod 8.
  auto stage = [&](int s) {
    const int m = (s & (DD - 1)) << 10;  // slot base (float index)
#pragma unroll
    for (int j = 0; j < 4; ++j) {
      __builtin_amdgcn_global_load_lds(
          (gp_t)(gsrc + (size_t)s * FF + j * 16),
          (lp_t)(&lds[m + (j << 8)]), 16, 0, 0);
    }
  };

  // read tile s from LDS into a register buffer (contiguous 16B/lane:
  // conflict-free ds_read_b128).
  auto ldsread = [&](float4 (&Xs)[4], int s) {
    const int m = (s & (DD - 1)) << 10;
#pragma unroll
    for (int j = 0; j < 4; ++j)
      Xs[j] = *reinterpret_cast<const float4*>(&lds[m + (j << 8) + (lane << 2)]);
  };

  // h-independent phase: projection FMAs + quad butterfly + bias fold
  auto proj = [&](const float4 (&Xs)[4], float& oaz, float& oar, float& osh) {
    f2 a01 = b01q, a23 = b23q, a45 = b45q, a67 = b67q;
    float a8 = b8q;
#pragma unroll
    for (int j = 0; j < 4; ++j) {
      const float4 v = Xs[j];
      const int sl = j * 4;
      a01 = v.x * w01[sl+0] + a01; a23 = v.x * w23[sl+0] + a23;
      a45 = v.x * w45[sl+0] + a45; a67 = v.x * w67[sl+0] + a67;
      a8 = fmaf(v.x, w8[sl+0], a8);
      a01 = v.y * w01[sl+1] + a01; a23 = v.y * w23[sl+1] + a23;
      a45 = v.y * w45[sl+1] + a45; a67 = v.y * w67[sl+1] + a67;
      a8 = fmaf(v.y, w8[sl+1], a8);
      a01 = v.z * w01[sl+2] + a01; a23 = v.z * w23[sl+2] + a23;
      a45 = v.z * w45[sl+2] + a45; a67 = v.z * w67[sl+2] + a67;
      a8 = fmaf(v.z, w8[sl+2], a8);
      a01 = v.w * w01[sl+3] + a01; a23 = v.w * w23[sl+3] + a23;
      a45 = v.w * w45[sl+3] + a45; a67 = v.w * w67[sl+3] + a67;
      a8 = fmaf(v.w, w8[sl+3], a8);
    }
    float s0 = a01.x, s1 = a01.y, s2 = a23.x, s3 = a23.y, s4 = a45.x,
          s5 = a45.y, s6 = a67.x, s7 = a67.y, s8 = a8;
    s0 += dpp_quad<0xB1>(s0); s1 += dpp_quad<0xB1>(s1); s2 += dpp_quad<0xB1>(s2);
    s3 += dpp_quad<0xB1>(s3); s4 += dpp_quad<0xB1>(s4); s5 += dpp_quad<0xB1>(s5);
    s6 += dpp_quad<0xB1>(s6); s7 += dpp_quad<0xB1>(s7); s8 += dpp_quad<0xB1>(s8);
    s0 += dpp_quad<0x4E>(s0); s1 += dpp_quad<0x4E>(s1); s2 += dpp_quad<0x4E>(s2);
    s3 += dpp_quad<0x4E>(s3); s4 += dpp_quad<0x4E>(s4); s5 += dpp_quad<0x4E>(s5);
    s6 += dpp_quad<0x4E>(s6); s7 += dpp_quad<0x4E>(s7); s8 += dpp_quad<0x4E>(s8);
    const float sz = (u == 0) ? s0 : ((u == 1) ? s1 : s2);
    const float sr = (u == 0) ? s3 : ((u == 1) ? s4 : s5);
    const float sh = (u == 0) ? s6 : ((u == 1) ? s7 : s8);
    oaz = sz + rbz;
    oar = sr + rbr;
    osh = sh;
  };

  // serial phase: the h-dependent gate chain
  auto gate = [&](float az, float ar, float sh) {
    const float iz = fmaf(h2, wz[2], fmaf(h1, wz[1], fmaf(h0, wz[0], az)));
    const float ir = fmaf(h2, wr[2], fmaf(h1, wr[1], fmaf(h0, wr[0], ar)));
    const float ih = fmaf(h2, wh[2], fmaf(h1, wh[1], fmaf(h0, wh[0], rbh)));
    const float z = fast_rcp(1.0f + fast_exp2(iz));
    const float r = fast_rcp(1.0f + fast_exp2(ir));
    const float t = fmaf(-2.0f, fast_rcp(1.0f + fast_exp2(fmaf(r, ih, sh))), 1.0f);
    const float hn = fmaf(z, hprev - t, t);
    hprev = hn;
    h0 = dpp_quad<0x00>(hn);
    h1 = dpp_quad<0x55>(hn);
    h2 = dpp_quad<0xAA>(hn);
  };

  float4 XA[4], XB[4];
  float az, ar, sh;

  // ---- prologue: fill the ring, pull tile 0 into registers
#pragma unroll
  for (int s0 = 0; s0 < DD; ++s0) stage(s0);
  VMWAIT(28);          // tile 0 landed; tiles 1..7 (28 ops) still in flight
  ldsread(XA, 0);

  // ---- main loop: steps 0..SS-DD-1 (248 steps, 124 iterations of 2)
  for (int s = 0; s < SS - DD; s += 2) {
    stage(s + DD);                // tiles 8..255 over the loop
    VMWAIT(28);                   // tile s+1 landed (7 newer tiles in flight)
    ldsread(XB, s + 1);
    proj(XA, az, ar, sh);
    gate(az, ar, sh);
    stage(s + 1 + DD);
    VMWAIT(28);                   // tile s+2 landed
    ldsread(XA, s + 2);
    proj(XB, az, ar, sh);
    gate(az, ar, sh);
  }

  // ---- epilogue: steps 248..255; one drain, then register double-buffer
  VMWAIT(0);
  ldsread(XB, 249); proj(XA, az, ar, sh); gate(az, ar, sh);  // step 248
  ldsread(XA, 250); proj(XB, az, ar, sh); gate(az, ar, sh);  // step 249
  ldsread(XB, 251); proj(XA, az, ar, sh); gate(az, ar, sh);  // step 250
  ldsread(XA, 252); proj(XB, az, ar, sh); gate(az, ar, sh);  // step 251
  ldsread(XB, 253); proj(XA, az, ar, sh); gate(az, ar, sh);  // step 252
  ldsread(XA, 254); proj(XB, az, ar, sh); gate(az, ar, sh);  // step 253
  ldsread(XB, 255); proj(XA, az, ar, sh); gate(az, ar, sh);  // step 254
  proj(XB, az, ar, sh); gate(az, ar, sh);                    // step 255

  // ---- dense (3 -> 10) + softmax; h0..h2 broadcast so all quad lanes agree
  float lg[10];
#pragma unroll
  for (int j = 0; j < 10; ++j)
    lg[j] = dense_b[j] + h0 * dense_w[j] + h1 * dense_w[10 + j] + h2 * dense_w[20 + j];
  float m = lg[0];
#pragma unroll
  for (int j = 1; j < 10; ++j) m = fmaxf(m, lg[j]);
  float e[10];
  float ssum = 0.0f;
#pragma unroll
  for (int j = 0; j < 10; ++j) {
    e[j] = fast_exp2(1.4426950408889634f * (lg[j] - m));
    ssum += e[j];
  }
  const float inv = fast_rcp(ssum);
#pragma unroll
  for (int j = u; j < 10; j += 4) out[(size_t)c * 10 + j] = e[j] * inv;
}

extern "C" void kernel_launch(void* const* d_in, const int* in_sizes, int n_in,
                              void* d_out, int out_size, void* d_ws, size_t ws_size,
                              hipStream_t stream) {
  const float* x      = (const float*)d_in[0];  // [4096,256,64]
  const float* kern   = (const float*)d_in[1];  // [64,9]
  const float* rkern  = (const float*)d_in[2];  // [3,9]
  const float* bias   = (const float*)d_in[3];  // [2,9]
  const float* dw     = (const float*)d_in[4];  // [3,10]
  const float* db     = (const float*)d_in[5];  // [10]
  float* out = (float*)d_out;

  fused_gru_kernel<<<BB / 16, 64, 0, stream>>>(x, kern, rkern, bias, dw, db, out);
}

// Round 8
// 91.232 us; speedup vs baseline: 1.7351x; 1.7351x over previous
//
#include <hip/hip_runtime.h>

// Problem constants (from reference setup_inputs)
#define BB 4096   // batch
#define SS 256    // sequence length
#define FF 64     // features
#define GG 9      // 3*U gate width

#define NEG_LOG2E -1.4426950408889634f
#define TWO_LOG2E  2.8853900817779268f

typedef float f2 __attribute__((ext_vector_type(2)));

#if __has_builtin(__builtin_amdgcn_exp2f)
__device__ __forceinline__ float fast_exp2(float x) { return __builtin_amdgcn_exp2f(x); }
#else
__device__ __forceinline__ float fast_exp2(float x) { return exp2f(x); }
#endif
#if __has_builtin(__builtin_amdgcn_rcpf)
__device__ __forceinline__ float fast_rcp(float x) { return __builtin_amdgcn_rcpf(x); }
#else
__device__ __forceinline__ float fast_rcp(float x) { return 1.0f / x; }
#endif

// Quad-lane DPP helper (verified absmax-0 in R3-R7).
template <int CTRL>
__device__ __forceinline__ float dpp_quad(float v) {
  return __int_as_float(
      __builtin_amdgcn_mov_dpp(__float_as_int(v), CTRL, 0xF, 0xF, true));
}

// -----------------------------------------------------------------------------
// Fully fused GRU — R5 structure (best: 90.8us) with the wave-occupancy fix.
// R5-R7 ran 256 waves total = 1 wave/CU = 1 busy SIMD of 4 (VALUBusy 14%/6.6%
// measured). R8: 4 chains per wave (16-thread blocks), 1024 blocks -> 1 wave
// on each of the chip's 1024 SIMDs. Per-SIMD instruction stream is identical
// to R5; per-CU memory traffic identical; but 4 independent waves per CU now
// overlap their memory stalls (TLP instead of the failed source-pipelining).
// Math/code otherwise byte-identical to the absmax-0 R5 kernel.
// -----------------------------------------------------------------------------
__global__ __launch_bounds__(16, 1) void fused_gru_kernel(
    const float* __restrict__ x,           // [B,S,F]
    const float* __restrict__ kernel_w,    // [F,9]
    const float* __restrict__ rec_kernel,  // [3,9]
    const float* __restrict__ bias,        // [2,9]
    const float* __restrict__ dense_w,     // [3,10]
    const float* __restrict__ dense_b,     // [10]
    float* __restrict__ out)               // [B,10]
{
  const int lane = threadIdx.x;        // 0..15 (one quarter-wave block)
  const int u    = lane & 3;           // quad slot (feature sub-slice / unit)
  const int uc   = (u < 3) ? u : 2;    // lane 3: clamp unit role (benign)
  const int c    = blockIdx.x * 4 + (lane >> 2);   // chain (batch) id

  // ---- input-projection weights for this lane's 16 features (pre-scaled)
  f2 w01[16], w23[16], w45[16], w67[16];
  float w8[16];
#pragma unroll
  for (int j = 0; j < 4; ++j)
#pragma unroll
    for (int e = 0; e < 4; ++e) {
      const int fi = j * 16 + u * 4 + e;   // feature index
      const int sl = j * 4 + e;            // register slot
      const float* kw = kernel_w + fi * GG;
      w01[sl] = (f2){kw[0] * NEG_LOG2E, kw[1] * NEG_LOG2E};
      w23[sl] = (f2){kw[2] * NEG_LOG2E, kw[3] * NEG_LOG2E};
      w45[sl] = (f2){kw[4] * NEG_LOG2E, kw[5] * NEG_LOG2E};
      w67[sl] = (f2){kw[6] * TWO_LOG2E, kw[7] * TWO_LOG2E};
      w8[sl]  = kw[8] * TWO_LOG2E;
    }

  // input bias, pre-scaled AND quartered (quad reduce restores exactly 1x).
  const f2 b01q = {bias[0] * NEG_LOG2E * 0.25f, bias[1] * NEG_LOG2E * 0.25f};
  const f2 b23q = {bias[2] * NEG_LOG2E * 0.25f, bias[3] * NEG_LOG2E * 0.25f};
  const f2 b45q = {bias[4] * NEG_LOG2E * 0.25f, bias[5] * NEG_LOG2E * 0.25f};
  const f2 b67q = {bias[6] * TWO_LOG2E * 0.25f, bias[7] * TWO_LOG2E * 0.25f};
  const float b8q = bias[8] * TWO_LOG2E * 0.25f;

  // recurrent weights/bias for this lane's unit (pre-scaled)
  float wz[3], wr[3], wh[3];
#pragma unroll
  for (int hh = 0; hh < 3; ++hh) {
    wz[hh] = rec_kernel[hh * GG + uc]     * NEG_LOG2E;
    wr[hh] = rec_kernel[hh * GG + 3 + uc] * NEG_LOG2E;
    wh[hh] = rec_kernel[hh * GG + 6 + uc] * TWO_LOG2E;
  }
  const float rbz = bias[GG + uc]     * NEG_LOG2E;
  const float rbr = bias[GG + 3 + uc] * NEG_LOG2E;
  const float rbh = bias[GG + 6 + uc] * TWO_LOG2E;

  float h0 = 0.0f, h1 = 0.0f, h2 = 0.0f, hprev = 0.0f;

  // per-lane x pointer: row (c, s) has 16 float4s; this lane reads col j*4+u.
  const float4* pc = reinterpret_cast<const float4*>(x) + (size_t)c * SS * 16 + u;

  float4 X0[4], X1[4], X2[4], X3[4];  // 4-step register ring, static indexing
  auto loads = [&](float4 (&Xs)[4], int s) {
#pragma unroll
    for (int j = 0; j < 4; ++j) Xs[j] = pc[(size_t)s * 16 + j * 4];
  };

  auto step = [&](const float4 (&Xs)[4]) {
    f2 a01 = b01q, a23 = b23q, a45 = b45q, a67 = b67q;
    float a8 = b8q;
#pragma unroll
    for (int j = 0; j < 4; ++j) {
      const float4 v = Xs[j];
      const int sl = j * 4;
      a01 = v.x * w01[sl+0] + a01; a23 = v.x * w23[sl+0] + a23;
      a45 = v.x * w45[sl+0] + a45; a67 = v.x * w67[sl+0] + a67;
      a8 = fmaf(v.x, w8[sl+0], a8);
      a01 = v.y * w01[sl+1] + a01; a23 = v.y * w23[sl+1] + a23;
      a45 = v.y * w45[sl+1] + a45; a67 = v.y * w67[sl+1] + a67;
      a8 = fmaf(v.y, w8[sl+1], a8);
      a01 = v.z * w01[sl+2] + a01; a23 = v.z * w23[sl+2] + a23;
      a45 = v.z * w45[sl+2] + a45; a67 = v.z * w67[sl+2] + a67;
      a8 = fmaf(v.z, w8[sl+2], a8);
      a01 = v.w * w01[sl+3] + a01; a23 = v.w * w23[sl+3] + a23;
      a45 = v.w * w45[sl+3] + a45; a67 = v.w * w67[sl+3] + a67;
      a8 = fmaf(v.w, w8[sl+3], a8);
    }
    // 2-stage butterfly over the quad -> every lane holds all 9 full dots
    float s0 = a01.x, s1 = a01.y, s2 = a23.x, s3 = a23.y, s4 = a45.x,
          s5 = a45.y, s6 = a67.x, s7 = a67.y, s8 = a8;
    s0 += dpp_quad<0xB1>(s0); s1 += dpp_quad<0xB1>(s1); s2 += dpp_quad<0xB1>(s2);
    s3 += dpp_quad<0xB1>(s3); s4 += dpp_quad<0xB1>(s4); s5 += dpp_quad<0xB1>(s5);
    s6 += dpp_quad<0xB1>(s6); s7 += dpp_quad<0xB1>(s7); s8 += dpp_quad<0xB1>(s8);
    s0 += dpp_quad<0x4E>(s0); s1 += dpp_quad<0x4E>(s1); s2 += dpp_quad<0x4E>(s2);
    s3 += dpp_quad<0x4E>(s3); s4 += dpp_quad<0x4E>(s4); s5 += dpp_quad<0x4E>(s5);
    s6 += dpp_quad<0x4E>(s6); s7 += dpp_quad<0x4E>(s7); s8 += dpp_quad<0x4E>(s8);
    // this lane's gates (z_u, r_u, h_u); lane 3 duplicates unit 2 (unused)
    const float sz = (u == 0) ? s0 : ((u == 1) ? s1 : s2);
    const float sr = (u == 0) ? s3 : ((u == 1) ? s4 : s5);
    const float sh = (u == 0) ? s6 : ((u == 1) ? s7 : s8);
    const float iz = fmaf(h2, wz[2], fmaf(h1, wz[1], fmaf(h0, wz[0], sz + rbz)));
    const float ir = fmaf(h2, wr[2], fmaf(h1, wr[1], fmaf(h0, wr[0], sr + rbr)));
    const float ih = fmaf(h2, wh[2], fmaf(h1, wh[1], fmaf(h0, wh[0], rbh)));
    const float z = fast_rcp(1.0f + fast_exp2(iz));
    const float r = fast_rcp(1.0f + fast_exp2(ir));
    const float t = fmaf(-2.0f, fast_rcp(1.0f + fast_exp2(fmaf(r, ih, sh))), 1.0f);
    const float hn = fmaf(z, hprev - t, t);
    hprev = hn;
    h0 = dpp_quad<0x00>(hn);
    h1 = dpp_quad<0x55>(hn);
    h2 = dpp_quad<0xAA>(hn);
  };

  loads(X0, 0); loads(X1, 1); loads(X2, 2); loads(X3, 3);
  for (int sg = 0; sg < SS; sg += 4) {
    step(X0); { int sn = sg + 4; if (sn >= SS) sn = SS - 4; loads(X0, sn); }
    step(X1); { int sn = sg + 5; if (sn >= SS) sn = SS - 4; loads(X1, sn); }
    step(X2); { int sn = sg + 6; if (sn >= SS) sn = SS - 4; loads(X2, sn); }
    step(X3); { int sn = sg + 7; if (sn >= SS) sn = SS - 4; loads(X3, sn); }
  }

  // Dense (3 -> 10) + softmax; h0..h2 broadcast so all quad lanes agree.
  float lg[10];
#pragma unroll
  for (int j = 0; j < 10; ++j)
    lg[j] = dense_b[j] + h0 * dense_w[j] + h1 * dense_w[10 + j] + h2 * dense_w[20 + j];
  float m = lg[0];
#pragma unroll
  for (int j = 1; j < 10; ++j) m = fmaxf(m, lg[j]);
  float e[10];
  float ssum = 0.0f;
#pragma unroll
  for (int j = 0; j < 10; ++j) {
    e[j] = fast_exp2(1.4426950408889634f * (lg[j] - m));
    ssum += e[j];
  }
  const float inv = fast_rcp(ssum);
#pragma unroll
  for (int j = u; j < 10; j += 4) out[(size_t)c * 10 + j] = e[j] * inv;
}

extern "C" void kernel_launch(void* const* d_in, const int* in_sizes, int n_in,
                              void* d_out, int out_size, void* d_ws, size_t ws_size,
                              hipStream_t stream) {
  const float* x      = (const float*)d_in[0];  // [4096,256,64]
  const float* kern   = (const float*)d_in[1];  // [64,9]
  const float* rkern  = (const float*)d_in[2];  // [3,9]
  const float* bias   = (const float*)d_in[3];  // [2,9]
  const float* dw     = (const float*)d_in[4];  // [3,10]
  const float* db     = (const float*)d_in[5];  // [10]
  float* out = (float*)d_out;

  // 4 chains per 16-thread block -> 1024 waves -> one per SIMD chip-wide.
  fused_gru_kernel<<<BB / 4, 16, 0, stream>>>(x, kern, rkern, bias, dw, db, out);
}

// Round 9
// 63.459 us; speedup vs baseline: 2.4945x; 1.4377x over previous
//
#include <hip/hip_runtime.h>

// Problem constants (from reference setup_inputs)
#define BB 4096   // batch
#define SS 256    // sequence length
#define FF 64     // features
#define GG 9      // 3*U gate width

#define NEG_LOG2E -1.4426950408889634f
#define TWO_LOG2E  2.8853900817779268f

typedef float f2 __attribute__((ext_vector_type(2)));

#if __has_builtin(__builtin_amdgcn_exp2f)
__device__ __forceinline__ float fast_exp2(float x) { return __builtin_amdgcn_exp2f(x); }
#else
__device__ __forceinline__ float fast_exp2(float x) { return exp2f(x); }
#endif
#if __has_builtin(__builtin_amdgcn_rcpf)
__device__ __forceinline__ float fast_rcp(float x) { return __builtin_amdgcn_rcpf(x); }
#else
__device__ __forceinline__ float fast_rcp(float x) { return 1.0f / x; }
#endif

// DPP helper: quad_perm (CTRL<0x100) and row ops (row_ror:N = 0x120+N).
template <int CTRL>
__device__ __forceinline__ float dpp_f(float v) {
  return __int_as_float(
      __builtin_amdgcn_mov_dpp(__float_as_int(v), CTRL, 0xF, 0xF, true));
}

// -----------------------------------------------------------------------------
// Fully fused GRU — R9: 16 lanes per chain -> 1024 full wave64s -> one wave on
// EVERY SIMD (R5/R8 could only ever occupy 256 of 1024 SIMDs; measured
// VALUBusy 14% = ~58% of one busy SIMD/CU). Per-wave work also shrinks:
//   - lane owns 4 features -> 1 float4 load /step (ring = 16 VGPRs total,
//     no R6-style allocator collapse), 20 FMA instrs;
//   - 16-lane sum = 4 single-instr DPP-add stages: quad_perm xor1, xor2,
//     then row_ror:4, row_ror:8 (rotate-accumulate over the 16-lane row);
//   - every quad redundantly runs the (absmax-0 verified) gate math, so the
//     h broadcast stays quad-local (same 3 quad_perm DPPs as R5).
// Input bias pre-scaled by 1/16 (power of two, exact): 16-lane reduce
// restores exactly 1x.
// -----------------------------------------------------------------------------
__global__ __launch_bounds__(64, 1) void fused_gru_kernel(
    const float* __restrict__ x,           // [B,S,F]
    const float* __restrict__ kernel_w,    // [F,9]
    const float* __restrict__ rec_kernel,  // [3,9]
    const float* __restrict__ bias,        // [2,9]
    const float* __restrict__ dense_w,     // [3,10]
    const float* __restrict__ dense_b,     // [10]
    float* __restrict__ out)               // [B,10]
{
  const int lane = threadIdx.x;        // 0..63
  const int fl   = lane & 15;          // feature-slot within the chain's row
  const int u    = lane & 3;           // gate-unit role within the quad
  const int uc   = (u < 3) ? u : 2;    // lane u==3: clamp unit role (benign)
  const int c    = blockIdx.x * 4 + (lane >> 4);   // chain (batch) id

  // ---- input-projection weights for this lane's 4 features (pre-scaled)
  f2 w01[4], w23[4], w45[4], w67[4];
  float w8[4];
#pragma unroll
  for (int e = 0; e < 4; ++e) {
    const float* kw = kernel_w + (fl * 4 + e) * GG;
    w01[e] = (f2){kw[0] * NEG_LOG2E, kw[1] * NEG_LOG2E};
    w23[e] = (f2){kw[2] * NEG_LOG2E, kw[3] * NEG_LOG2E};
    w45[e] = (f2){kw[4] * NEG_LOG2E, kw[5] * NEG_LOG2E};
    w67[e] = (f2){kw[6] * TWO_LOG2E, kw[7] * TWO_LOG2E};
    w8[e]  = kw[8] * TWO_LOG2E;
  }

  // input bias, pre-scaled and SIXTEENTH'd (16-lane reduce restores 1x).
  const float Q = 0.0625f;
  const f2 b01q = {bias[0] * NEG_LOG2E * Q, bias[1] * NEG_LOG2E * Q};
  const f2 b23q = {bias[2] * NEG_LOG2E * Q, bias[3] * NEG_LOG2E * Q};
  const f2 b45q = {bias[4] * NEG_LOG2E * Q, bias[5] * NEG_LOG2E * Q};
  const f2 b67q = {bias[6] * TWO_LOG2E * Q, bias[7] * TWO_LOG2E * Q};
  const float b8q = bias[8] * TWO_LOG2E * Q;

  // recurrent weights/bias for this lane's unit (pre-scaled)
  float wz[3], wr[3], wh[3];
#pragma unroll
  for (int hh = 0; hh < 3; ++hh) {
    wz[hh] = rec_kernel[hh * GG + uc]     * NEG_LOG2E;
    wr[hh] = rec_kernel[hh * GG + 3 + uc] * NEG_LOG2E;
    wh[hh] = rec_kernel[hh * GG + 6 + uc] * TWO_LOG2E;
  }
  const float rbz = bias[GG + uc]     * NEG_LOG2E;
  const float rbr = bias[GG + 3 + uc] * NEG_LOG2E;
  const float rbh = bias[GG + 6 + uc] * TWO_LOG2E;

  float h0 = 0.0f, h1 = 0.0f, h2 = 0.0f, hprev = 0.0f;

  // per-lane x pointer: row (c,s) = 16 float4s; this lane reads float4 #fl.
  const float4* pc = reinterpret_cast<const float4*>(x) + (size_t)c * SS * 16 + fl;

  float4 X0, X1, X2, X3;  // 4-step register ring (16 VGPRs)

  auto step = [&](const float4 v) {
    // projection over this lane's 4 features (20 instrs, f2-packed)
    f2 a01 = b01q, a23 = b23q, a45 = b45q, a67 = b67q;
    float a8 = b8q;
    a01 = v.x * w01[0] + a01; a23 = v.x * w23[0] + a23;
    a45 = v.x * w45[0] + a45; a67 = v.x * w67[0] + a67;
    a8 = fmaf(v.x, w8[0], a8);
    a01 = v.y * w01[1] + a01; a23 = v.y * w23[1] + a23;
    a45 = v.y * w45[1] + a45; a67 = v.y * w67[1] + a67;
    a8 = fmaf(v.y, w8[1], a8);
    a01 = v.z * w01[2] + a01; a23 = v.z * w23[2] + a23;
    a45 = v.z * w45[2] + a45; a67 = v.z * w67[2] + a67;
    a8 = fmaf(v.z, w8[2], a8);
    a01 = v.w * w01[3] + a01; a23 = v.w * w23[3] + a23;
    a45 = v.w * w45[3] + a45; a67 = v.w * w67[3] + a67;
    a8 = fmaf(v.w, w8[3], a8);

    // 16-lane reduce: xor1, xor2 (quad_perm), then rotate-accumulate
    // across quads (row_ror:4 = 0x124, row_ror:8 = 0x128). 36 instrs.
    float s0 = a01.x, s1 = a01.y, s2 = a23.x, s3 = a23.y, s4 = a45.x,
          s5 = a45.y, s6 = a67.x, s7 = a67.y, s8 = a8;
    s0 += dpp_f<0xB1>(s0); s1 += dpp_f<0xB1>(s1); s2 += dpp_f<0xB1>(s2);
    s3 += dpp_f<0xB1>(s3); s4 += dpp_f<0xB1>(s4); s5 += dpp_f<0xB1>(s5);
    s6 += dpp_f<0xB1>(s6); s7 += dpp_f<0xB1>(s7); s8 += dpp_f<0xB1>(s8);
    s0 += dpp_f<0x4E>(s0); s1 += dpp_f<0x4E>(s1); s2 += dpp_f<0x4E>(s2);
    s3 += dpp_f<0x4E>(s3); s4 += dpp_f<0x4E>(s4); s5 += dpp_f<0x4E>(s5);
    s6 += dpp_f<0x4E>(s6); s7 += dpp_f<0x4E>(s7); s8 += dpp_f<0x4E>(s8);
    s0 += dpp_f<0x124>(s0); s1 += dpp_f<0x124>(s1); s2 += dpp_f<0x124>(s2);
    s3 += dpp_f<0x124>(s3); s4 += dpp_f<0x124>(s4); s5 += dpp_f<0x124>(s5);
    s6 += dpp_f<0x124>(s6); s7 += dpp_f<0x124>(s7); s8 += dpp_f<0x124>(s8);
    s0 += dpp_f<0x128>(s0); s1 += dpp_f<0x128>(s1); s2 += dpp_f<0x128>(s2);
    s3 += dpp_f<0x128>(s3); s4 += dpp_f<0x128>(s4); s5 += dpp_f<0x128>(s5);
    s6 += dpp_f<0x128>(s6); s7 += dpp_f<0x128>(s7); s8 += dpp_f<0x128>(s8);

    // gates (each quad computes the same thing redundantly; absmax-0 math)
    const float sz = (u == 0) ? s0 : ((u == 1) ? s1 : s2);
    const float sr = (u == 0) ? s3 : ((u == 1) ? s4 : s5);
    const float sh = (u == 0) ? s6 : ((u == 1) ? s7 : s8);
    const float iz = fmaf(h2, wz[2], fmaf(h1, wz[1], fmaf(h0, wz[0], sz + rbz)));
    const float ir = fmaf(h2, wr[2], fmaf(h1, wr[1], fmaf(h0, wr[0], sr + rbr)));
    const float ih = fmaf(h2, wh[2], fmaf(h1, wh[1], fmaf(h0, wh[0], rbh)));
    const float z = fast_rcp(1.0f + fast_exp2(iz));
    const float r = fast_rcp(1.0f + fast_exp2(ir));
    const float t = fmaf(-2.0f, fast_rcp(1.0f + fast_exp2(fmaf(r, ih, sh))), 1.0f);
    const float hn = fmaf(z, hprev - t, t);
    hprev = hn;
    h0 = dpp_f<0x00>(hn);   // quad_perm [0,0,0,0]
    h1 = dpp_f<0x55>(hn);   // quad_perm [1,1,1,1]
    h2 = dpp_f<0xAA>(hn);   // quad_perm [2,2,2,2]
  };

  X0 = pc[0 * 16]; X1 = pc[1 * 16]; X2 = pc[2 * 16]; X3 = pc[3 * 16];
  for (int sg = 0; sg < SS; sg += 4) {
    step(X0); { int sn = sg + 4; if (sn >= SS) sn = SS - 4; X0 = pc[(size_t)sn * 16]; }
    step(X1); { int sn = sg + 5; if (sn >= SS) sn = SS - 4; X1 = pc[(size_t)sn * 16]; }
    step(X2); { int sn = sg + 6; if (sn >= SS) sn = SS - 4; X2 = pc[(size_t)sn * 16]; }
    step(X3); { int sn = sg + 7; if (sn >= SS) sn = SS - 4; X3 = pc[(size_t)sn * 16]; }
  }

  // Dense (3 -> 10) + softmax; only quad 0 of each chain row writes.
  if (fl < 4) {
    float lg[10];
#pragma unroll
    for (int j = 0; j < 10; ++j)
      lg[j] = dense_b[j] + h0 * dense_w[j] + h1 * dense_w[10 + j] + h2 * dense_w[20 + j];
    float m = lg[0];
#pragma unroll
    for (int j = 1; j < 10; ++j) m = fmaxf(m, lg[j]);
    float e[10];
    float ssum = 0.0f;
#pragma unroll
    for (int j = 0; j < 10; ++j) {
      e[j] = fast_exp2(1.4426950408889634f * (lg[j] - m));
      ssum += e[j];
    }
    const float inv = fast_rcp(ssum);
#pragma unroll
    for (int j = u; j < 10; j += 4) out[(size_t)c * 10 + j] = e[j] * inv;
  }
}

extern "C" void kernel_launch(void* const* d_in, const int* in_sizes, int n_in,
                              void* d_out, int out_size, void* d_ws, size_t ws_size,
                              hipStream_t stream) {
  const float* x      = (const float*)d_in[0];  // [4096,256,64]
  const float* kern   = (const float*)d_in[1];  // [64,9]
  const float* rkern  = (const float*)d_in[2];  // [3,9]
  const float* bias   = (const float*)d_in[3];  // [2,9]
  const float* dw     = (const float*)d_in[4];  // [3,10]
  const float* db     = (const float*)d_in[5];  // [10]
  float* out = (float*)d_out;

  // 4 chains x 16 lanes per 64-thread block; 1024 blocks -> 1 wave per SIMD
  // on all 1024 SIMDs.
  fused_gru_kernel<<<BB / 4, 64, 0, stream>>>(x, kern, rkern, bias, dw, db, out);
}

// Round 10
// 61.023 us; speedup vs baseline: 2.5940x; 1.0399x over previous
//
#include <hip/hip_runtime.h>

// Problem constants (from reference setup_inputs)
#define BB 4096   // batch
#define SS 256    // sequence length
#define FF 64     // features
#define GG 9      // 3*U gate width

#define NEG_LOG2E -1.4426950408889634f
#define TWO_LOG2E  2.8853900817779268f

typedef float f2 __attribute__((ext_vector_type(2)));

#if __has_builtin(__builtin_amdgcn_exp2f)
__device__ __forceinline__ float fast_exp2(float x) { return __builtin_amdgcn_exp2f(x); }
#else
__device__ __forceinline__ float fast_exp2(float x) { return exp2f(x); }
#endif
#if __has_builtin(__builtin_amdgcn_rcpf)
__device__ __forceinline__ float fast_rcp(float x) { return __builtin_amdgcn_rcpf(x); }
#else
__device__ __forceinline__ float fast_rcp(float x) { return 1.0f / x; }
#endif

// DPP helper: quad_perm (CTRL<0x100) and row ops (row_ror:N = 0x120+N).
template <int CTRL>
__device__ __forceinline__ float dpp_f(float v) {
  return __int_as_float(
      __builtin_amdgcn_mov_dpp(__float_as_int(v), CTRL, 0xF, 0xF, true));
}

// -----------------------------------------------------------------------------
// Fully fused GRU — R10 = R9 (63.5us, absmax 0) + depth-8 prefetch ring.
// R9 analysis: issue floor ~17.5us, memory floor ~20-30us, measured ~60us
// -> ~60% exposed stalls at 1 wave/SIMD (no TLP). Depth-8 ring = 8KB/wave
// in flight, ~1300cy cover (vs depth-4's 4KB/~650cy) while buffer VGPRs
// stay at 32 (R6's allocator collapse needed 128 buffer regs; safe here).
// Everything else byte-identical to R9.
// -----------------------------------------------------------------------------
__global__ __launch_bounds__(64, 1) void fused_gru_kernel(
    const float* __restrict__ x,           // [B,S,F]
    const float* __restrict__ kernel_w,    // [F,9]
    const float* __restrict__ rec_kernel,  // [3,9]
    const float* __restrict__ bias,        // [2,9]
    const float* __restrict__ dense_w,     // [3,10]
    const float* __restrict__ dense_b,     // [10]
    float* __restrict__ out)               // [B,10]
{
  const int lane = threadIdx.x;        // 0..63
  const int fl   = lane & 15;          // feature-slot within the chain's row
  const int u    = lane & 3;           // gate-unit role within the quad
  const int uc   = (u < 3) ? u : 2;    // lane u==3: clamp unit role (benign)
  const int c    = blockIdx.x * 4 + (lane >> 4);   // chain (batch) id

  // ---- input-projection weights for this lane's 4 features (pre-scaled)
  f2 w01[4], w23[4], w45[4], w67[4];
  float w8[4];
#pragma unroll
  for (int e = 0; e < 4; ++e) {
    const float* kw = kernel_w + (fl * 4 + e) * GG;
    w01[e] = (f2){kw[0] * NEG_LOG2E, kw[1] * NEG_LOG2E};
    w23[e] = (f2){kw[2] * NEG_LOG2E, kw[3] * NEG_LOG2E};
    w45[e] = (f2){kw[4] * NEG_LOG2E, kw[5] * NEG_LOG2E};
    w67[e] = (f2){kw[6] * TWO_LOG2E, kw[7] * TWO_LOG2E};
    w8[e]  = kw[8] * TWO_LOG2E;
  }

  // input bias, pre-scaled and SIXTEENTH'd (16-lane reduce restores 1x).
  const float Q = 0.0625f;
  const f2 b01q = {bias[0] * NEG_LOG2E * Q, bias[1] * NEG_LOG2E * Q};
  const f2 b23q = {bias[2] * NEG_LOG2E * Q, bias[3] * NEG_LOG2E * Q};
  const f2 b45q = {bias[4] * NEG_LOG2E * Q, bias[5] * NEG_LOG2E * Q};
  const f2 b67q = {bias[6] * TWO_LOG2E * Q, bias[7] * TWO_LOG2E * Q};
  const float b8q = bias[8] * TWO_LOG2E * Q;

  // recurrent weights/bias for this lane's unit (pre-scaled)
  float wz[3], wr[3], wh[3];
#pragma unroll
  for (int hh = 0; hh < 3; ++hh) {
    wz[hh] = rec_kernel[hh * GG + uc]     * NEG_LOG2E;
    wr[hh] = rec_kernel[hh * GG + 3 + uc] * NEG_LOG2E;
    wh[hh] = rec_kernel[hh * GG + 6 + uc] * TWO_LOG2E;
  }
  const float rbz = bias[GG + uc]     * NEG_LOG2E;
  const float rbr = bias[GG + 3 + uc] * NEG_LOG2E;
  const float rbh = bias[GG + 6 + uc] * TWO_LOG2E;

  float h0 = 0.0f, h1 = 0.0f, h2 = 0.0f, hprev = 0.0f;

  // per-lane x pointer: row (c,s) = 16 float4s; this lane reads float4 #fl.
  const float4* pc = reinterpret_cast<const float4*>(x) + (size_t)c * SS * 16 + fl;

  // depth-8 register ring (32 VGPRs), named buffers, static indexing
  float4 X0, X1, X2, X3, X4, X5, X6, X7;

  auto step = [&](const float4 v) {
    // projection over this lane's 4 features (20 instrs, f2-packed)
    f2 a01 = b01q, a23 = b23q, a45 = b45q, a67 = b67q;
    float a8 = b8q;
    a01 = v.x * w01[0] + a01; a23 = v.x * w23[0] + a23;
    a45 = v.x * w45[0] + a45; a67 = v.x * w67[0] + a67;
    a8 = fmaf(v.x, w8[0], a8);
    a01 = v.y * w01[1] + a01; a23 = v.y * w23[1] + a23;
    a45 = v.y * w45[1] + a45; a67 = v.y * w67[1] + a67;
    a8 = fmaf(v.y, w8[1], a8);
    a01 = v.z * w01[2] + a01; a23 = v.z * w23[2] + a23;
    a45 = v.z * w45[2] + a45; a67 = v.z * w67[2] + a67;
    a8 = fmaf(v.z, w8[2], a8);
    a01 = v.w * w01[3] + a01; a23 = v.w * w23[3] + a23;
    a45 = v.w * w45[3] + a45; a67 = v.w * w67[3] + a67;
    a8 = fmaf(v.w, w8[3], a8);

    // 16-lane reduce: xor1, xor2 (quad_perm), then rotate-accumulate
    // across quads (row_ror:4 = 0x124, row_ror:8 = 0x128). 36 instrs.
    float s0 = a01.x, s1 = a01.y, s2 = a23.x, s3 = a23.y, s4 = a45.x,
          s5 = a45.y, s6 = a67.x, s7 = a67.y, s8 = a8;
    s0 += dpp_f<0xB1>(s0); s1 += dpp_f<0xB1>(s1); s2 += dpp_f<0xB1>(s2);
    s3 += dpp_f<0xB1>(s3); s4 += dpp_f<0xB1>(s4); s5 += dpp_f<0xB1>(s5);
    s6 += dpp_f<0xB1>(s6); s7 += dpp_f<0xB1>(s7); s8 += dpp_f<0xB1>(s8);
    s0 += dpp_f<0x4E>(s0); s1 += dpp_f<0x4E>(s1); s2 += dpp_f<0x4E>(s2);
    s3 += dpp_f<0x4E>(s3); s4 += dpp_f<0x4E>(s4); s5 += dpp_f<0x4E>(s5);
    s6 += dpp_f<0x4E>(s6); s7 += dpp_f<0x4E>(s7); s8 += dpp_f<0x4E>(s8);
    s0 += dpp_f<0x124>(s0); s1 += dpp_f<0x124>(s1); s2 += dpp_f<0x124>(s2);
    s3 += dpp_f<0x124>(s3); s4 += dpp_f<0x124>(s4); s5 += dpp_f<0x124>(s5);
    s6 += dpp_f<0x124>(s6); s7 += dpp_f<0x124>(s7); s8 += dpp_f<0x124>(s8);
    s0 += dpp_f<0x128>(s0); s1 += dpp_f<0x128>(s1); s2 += dpp_f<0x128>(s2);
    s3 += dpp_f<0x128>(s3); s4 += dpp_f<0x128>(s4); s5 += dpp_f<0x128>(s5);
    s6 += dpp_f<0x128>(s6); s7 += dpp_f<0x128>(s7); s8 += dpp_f<0x128>(s8);

    // gates (each quad computes the same thing redundantly; absmax-0 math)
    const float sz = (u == 0) ? s0 : ((u == 1) ? s1 : s2);
    const float sr = (u == 0) ? s3 : ((u == 1) ? s4 : s5);
    const float sh = (u == 0) ? s6 : ((u == 1) ? s7 : s8);
    const float iz = fmaf(h2, wz[2], fmaf(h1, wz[1], fmaf(h0, wz[0], sz + rbz)));
    const float ir = fmaf(h2, wr[2], fmaf(h1, wr[1], fmaf(h0, wr[0], sr + rbr)));
    const float ih = fmaf(h2, wh[2], fmaf(h1, wh[1], fmaf(h0, wh[0], rbh)));
    const float z = fast_rcp(1.0f + fast_exp2(iz));
    const float r = fast_rcp(1.0f + fast_exp2(ir));
    const float t = fmaf(-2.0f, fast_rcp(1.0f + fast_exp2(fmaf(r, ih, sh))), 1.0f);
    const float hn = fmaf(z, hprev - t, t);
    hprev = hn;
    h0 = dpp_f<0x00>(hn);   // quad_perm [0,0,0,0]
    h1 = dpp_f<0x55>(hn);   // quad_perm [1,1,1,1]
    h2 = dpp_f<0xAA>(hn);   // quad_perm [2,2,2,2]
  };

  // branchless prefetch-index clamp: tail re-reads step SS-1 (L1-hit, free)
  auto pf = [&](int sn) -> float4 {
    sn = (sn < SS) ? sn : (SS - 1);
    return pc[(size_t)sn * 16];
  };

  X0 = pf(0); X1 = pf(1); X2 = pf(2); X3 = pf(3);
  X4 = pf(4); X5 = pf(5); X6 = pf(6); X7 = pf(7);

  for (int sg = 0; sg < SS; sg += 8) {
    step(X0); X0 = pf(sg + 8);
    step(X1); X1 = pf(sg + 9);
    step(X2); X2 = pf(sg + 10);
    step(X3); X3 = pf(sg + 11);
    step(X4); X4 = pf(sg + 12);
    step(X5); X5 = pf(sg + 13);
    step(X6); X6 = pf(sg + 14);
    step(X7); X7 = pf(sg + 15);
  }

  // Dense (3 -> 10) + softmax; only quad 0 of each chain row writes.
  if (fl < 4) {
    float lg[10];
#pragma unroll
    for (int j = 0; j < 10; ++j)
      lg[j] = dense_b[j] + h0 * dense_w[j] + h1 * dense_w[10 + j] + h2 * dense_w[20 + j];
    float m = lg[0];
#pragma unroll
    for (int j = 1; j < 10; ++j) m = fmaxf(m, lg[j]);
    float e[10];
    float ssum = 0.0f;
#pragma unroll
    for (int j = 0; j < 10; ++j) {
      e[j] = fast_exp2(1.4426950408889634f * (lg[j] - m));
      ssum += e[j];
    }
    const float inv = fast_rcp(ssum);
#pragma unroll
    for (int j = u; j < 10; j += 4) out[(size_t)c * 10 + j] = e[j] * inv;
  }
}

extern "C" void kernel_launch(void* const* d_in, const int* in_sizes, int n_in,
                              void* d_out, int out_size, void* d_ws, size_t ws_size,
                              hipStream_t stream) {
  const float* x      = (const float*)d_in[0];  // [4096,256,64]
  const float* kern   = (const float*)d_in[1];  // [64,9]
  const float* rkern  = (const float*)d_in[2];  // [3,9]
  const float* bias   = (const float*)d_in[3];  // [2,9]
  const float* dw     = (const float*)d_in[4];  // [3,10]
  const float* db     = (const float*)d_in[5];  // [10]
  float* out = (float*)d_out;

  // 4 chains x 16 lanes per 64-thread block; 1024 blocks -> 1 wave per SIMD
  // on all 1024 SIMDs.
  fused_gru_kernel<<<BB / 4, 64, 0, stream>>>(x, kern, rkern, bias, dw, db, out);
}